// Round 1
// baseline (242.496 us; speedup 1.0000x reference)
//
#include <hip/hip_runtime.h>

#define ED 256
#define NHEAD 8
#define NPTS 8
#define DHEAD 32

// ---------------------------------------------------------------------------
// Kernel A: per-batch precompute. query is [bs,1,ED] broadcast over all query
// positions, so relu(q@W_off+b) [128] and softmax(relu(q@W_attn+b)) [64]
// depend only on batch. ws layout per batch: off[128] then aw[64] (192 floats).
// ---------------------------------------------------------------------------
__global__ __launch_bounds__(256) void precompute_kernel(
    const float* __restrict__ query,
    const float* __restrict__ W_off, const float* __restrict__ b_off,
    const float* __restrict__ W_attn, const float* __restrict__ b_attn,
    float* __restrict__ ws)
{
    const int b = blockIdx.x;
    const int t = threadIdx.x;
    __shared__ float sq[ED];
    __shared__ float sattn[NHEAD * NPTS];

    sq[t] = query[b * ED + t];
    __syncthreads();

    if (t < 128) {
        // offset column t: coalesced across threads for each k
        float acc = b_off[t];
        #pragma unroll 8
        for (int k = 0; k < ED; ++k) acc = fmaf(sq[k], W_off[k * 128 + t], acc);
        ws[b * 192 + t] = fmaxf(acc, 0.0f);
    } else if (t < 192) {
        const int j = t - 128;
        float acc = b_attn[j];
        #pragma unroll 8
        for (int k = 0; k < ED; ++k) acc = fmaf(sq[k], W_attn[k * 64 + j], acc);
        sattn[j] = fmaxf(acc, 0.0f);
    }
    __syncthreads();

    if (t >= 128 && t < 192) {
        const int j = t - 128;
        const int hh = j >> 3;                 // head
        float m = -1e30f;
        #pragma unroll
        for (int p = 0; p < NPTS; ++p) m = fmaxf(m, sattn[hh * NPTS + p]);
        float s = 0.0f;
        #pragma unroll
        for (int p = 0; p < NPTS; ++p) s += expf(sattn[hh * NPTS + p] - m);
        ws[b * 192 + 128 + j] = expf(sattn[j] - m) / s;
    }
}

// ---------------------------------------------------------------------------
// Kernel B: one block (256 thr) per (batch, query). Thread t -> head t/32,
// channel t%32. 8 points x 4 bilinear corners = 32 gathers/thread, each
// coalesced 128B across the head-group. Then residual + LayerNorm over 256.
// blockIdx % bs -> batch keeps batch b's 4MB feature map resident in XCD
// (b%8)'s L2.
// ---------------------------------------------------------------------------
__global__ __launch_bounds__(256) void deform_attn_kernel(
    const float* __restrict__ feat,     // [bs, nq, NHEAD, DHEAD]
    const float* __restrict__ ref2d,    // [bs, nq, 1, 2]
    const float* __restrict__ query,    // [bs, 1, ED]
    const float* __restrict__ ln_g, const float* __restrict__ ln_b,
    const float* __restrict__ ws,       // [bs, 192]
    const int* __restrict__ Hp, const int* __restrict__ Wp,
    float* __restrict__ out,            // [bs, nq, ED]
    int nq, int bs)
{
    const int bq = blockIdx.x;
    const int b = bq % bs;              // XCD swizzle: batch b -> XCD b (bs==8)
    const int q = bq / bs;
    const int t = threadIdx.x;
    const int hh = t >> 5;              // head
    const int dd = t & 31;              // channel within head

    __shared__ float s_off[128];
    __shared__ float s_aw[64];
    __shared__ float s_ref[2];
    __shared__ float s_red[8];

    if (t < 128)      s_off[t] = ws[b * 192 + t];
    else if (t < 192) s_aw[t - 128] = ws[b * 192 + t];
    if (t == 0) {
        s_ref[0] = ref2d[(b * nq + q) * 2 + 0];
        s_ref[1] = ref2d[(b * nq + q) * 2 + 1];
    }
    const int H = Hp[0];
    const int W = Wp[0];
    __syncthreads();

    // pixel coords: x = ref_x*W + off_x - 0.5 ; y = ref_y*H + off_y - 0.5
    const float refx = s_ref[0] * (float)W - 0.5f;
    const float refy = s_ref[1] * (float)H - 0.5f;

    const float* fb = feat + (size_t)b * nq * ED + hh * DHEAD + dd;

    float acc = 0.0f;
    #pragma unroll
    for (int p = 0; p < NPTS; ++p) {
        const float x = refx + s_off[(hh * NPTS + p) * 2 + 0];
        const float y = refy + s_off[(hh * NPTS + p) * 2 + 1];
        const float xf = floorf(x);
        const float yf = floorf(y);
        const int ix = (int)xf;
        const int iy = (int)yf;
        const float wx = x - xf;
        const float wy = y - yf;

        const bool vx0 = (ix >= 0) && (ix < W);
        const bool vx1 = (ix + 1 >= 0) && (ix + 1 < W);
        const bool vy0 = (iy >= 0) && (iy < H);
        const bool vy1 = (iy + 1 >= 0) && (iy + 1 < H);
        const int cx0 = min(max(ix, 0), W - 1);
        const int cx1 = min(max(ix + 1, 0), W - 1);
        const int cy0 = min(max(iy, 0), H - 1);
        const int cy1 = min(max(iy + 1, 0), H - 1);

        const float s00 = (vx0 && vy0) ? fb[(size_t)(cy0 * W + cx0) * ED] : 0.0f;
        const float s01 = (vx1 && vy0) ? fb[(size_t)(cy0 * W + cx1) * ED] : 0.0f;
        const float s10 = (vx0 && vy1) ? fb[(size_t)(cy1 * W + cx0) * ED] : 0.0f;
        const float s11 = (vx1 && vy1) ? fb[(size_t)(cy1 * W + cx1) * ED] : 0.0f;

        const float top = s00 * (1.0f - wx) + s01 * wx;
        const float bot = s10 * (1.0f - wx) + s11 * wx;
        const float bil = top * (1.0f - wy) + bot * wy;
        acc = fmaf(s_aw[hh * NPTS + p], bil, acc);
    }

    // residual + LayerNorm over ED=256 (4 waves)
    const float res = acc + query[b * ED + t];
    float s = res;
    float ss = res * res;
    #pragma unroll
    for (int m = 1; m < 64; m <<= 1) {
        s  += __shfl_xor(s, m, 64);
        ss += __shfl_xor(ss, m, 64);
    }
    const int wid = t >> 6;
    if ((t & 63) == 0) { s_red[wid] = s; s_red[4 + wid] = ss; }
    __syncthreads();
    const float S  = s_red[0] + s_red[1] + s_red[2] + s_red[3];
    const float SS = s_red[4] + s_red[5] + s_red[6] + s_red[7];
    const float mean = S * (1.0f / ED);
    const float var  = SS * (1.0f / ED) - mean * mean;
    const float inv  = rsqrtf(var + 1e-5f);

    out[((size_t)b * nq + q) * ED + t] = (res - mean) * inv * ln_g[t] + ln_b[t];
}

extern "C" void kernel_launch(void* const* d_in, const int* in_sizes, int n_in,
                              void* d_out, int out_size, void* d_ws, size_t ws_size,
                              hipStream_t stream)
{
    const float* query  = (const float*)d_in[0];
    const float* feat   = (const float*)d_in[1];
    const float* ref2d  = (const float*)d_in[2];
    const float* W_off  = (const float*)d_in[3];
    const float* b_off  = (const float*)d_in[4];
    const float* W_attn = (const float*)d_in[5];
    const float* b_attn = (const float*)d_in[6];
    const float* ln_g   = (const float*)d_in[7];
    const float* ln_b   = (const float*)d_in[8];
    const int*   Hp     = (const int*)d_in[9];
    const int*   Wp     = (const int*)d_in[10];
    float* out = (float*)d_out;
    float* ws  = (float*)d_ws;

    const int bs = in_sizes[0] / ED;            // 8
    const int nq = in_sizes[2] / (bs * 2);      // h*w = 4096

    precompute_kernel<<<bs, 256, 0, stream>>>(query, W_off, b_off, W_attn, b_attn, ws);
    deform_attn_kernel<<<bs * nq, 256, 0, stream>>>(feat, ref2d, query, ln_g, ln_b,
                                                    ws, Hp, Wp, out, nq, bs);
}

// Round 2
// 145.485 us; speedup vs baseline: 1.6668x; 1.6668x over previous
//
#include <hip/hip_runtime.h>

#define ED 256
#define NHEAD 8
#define NPTS 8
#define DHEAD 32

// ---------------------------------------------------------------------------
// Kernel A: per-batch precompute. query is [bs,1,ED] broadcast over all query
// positions, so relu(q@W_off+b) [128] and softmax(relu(q@W_attn+b)) [64]
// depend only on batch. ws layout per batch: off[128] then aw[64] (192 floats).
// ---------------------------------------------------------------------------
__global__ __launch_bounds__(256) void precompute_kernel(
    const float* __restrict__ query,
    const float* __restrict__ W_off, const float* __restrict__ b_off,
    const float* __restrict__ W_attn, const float* __restrict__ b_attn,
    float* __restrict__ ws)
{
    const int b = blockIdx.x;
    const int t = threadIdx.x;
    __shared__ float sq[ED];
    __shared__ float sattn[NHEAD * NPTS];

    sq[t] = query[b * ED + t];
    __syncthreads();

    if (t < 128) {
        float a0 = 0.f, a1 = 0.f, a2 = 0.f, a3 = 0.f;
        #pragma unroll 4
        for (int k = 0; k < ED; k += 4) {
            a0 = fmaf(sq[k + 0], W_off[(k + 0) * 128 + t], a0);
            a1 = fmaf(sq[k + 1], W_off[(k + 1) * 128 + t], a1);
            a2 = fmaf(sq[k + 2], W_off[(k + 2) * 128 + t], a2);
            a3 = fmaf(sq[k + 3], W_off[(k + 3) * 128 + t], a3);
        }
        ws[b * 192 + t] = fmaxf(b_off[t] + ((a0 + a1) + (a2 + a3)), 0.0f);
    } else if (t < 192) {
        const int j = t - 128;
        float a0 = 0.f, a1 = 0.f, a2 = 0.f, a3 = 0.f;
        #pragma unroll 4
        for (int k = 0; k < ED; k += 4) {
            a0 = fmaf(sq[k + 0], W_attn[(k + 0) * 64 + j], a0);
            a1 = fmaf(sq[k + 1], W_attn[(k + 1) * 64 + j], a1);
            a2 = fmaf(sq[k + 2], W_attn[(k + 2) * 64 + j], a2);
            a3 = fmaf(sq[k + 3], W_attn[(k + 3) * 64 + j], a3);
        }
        sattn[j] = fmaxf(b_attn[j] + ((a0 + a1) + (a2 + a3)), 0.0f);
    }
    __syncthreads();

    if (t >= 128 && t < 192) {
        const int j = t - 128;
        const int hh = j >> 3;
        float m = -1e30f;
        #pragma unroll
        for (int p = 0; p < NPTS; ++p) m = fmaxf(m, sattn[hh * NPTS + p]);
        float s = 0.0f;
        #pragma unroll
        for (int p = 0; p < NPTS; ++p) s += expf(sattn[hh * NPTS + p] - m);
        ws[b * 192 + 128 + j] = expf(sattn[j] - m) / s;
    }
}

// ---------------------------------------------------------------------------
// Kernel B v2: block = 256 thr = 4 waves; wave w handles one query entirely
// (64 lanes x float4 = 256 channels). Phase 1: 256 threads compute the 4x64
// (q_local, head, point) coordinate/weight tuples 1:1, folding aw + validity
// into 4 corner weights; stash {int4 idx, float4 w} in LDS, layout [q][p][h]
// (2-way bank aliasing on read = free). Phase 2: per point 2x ds_read_b128 +
// 4x global_load_dwordx4 + 16 FMA. Phase 3: wave-local residual+LayerNorm.
// blockIdx % bs pins batch b to XCD b (bs==8): its 4MB feat map lives in one
// XCD's L2.
// ---------------------------------------------------------------------------
__global__ __launch_bounds__(256) void deform_attn_kernel(
    const float* __restrict__ feat,     // [bs, nq, NHEAD, DHEAD]
    const float* __restrict__ ref2d,    // [bs, nq, 1, 2]
    const float* __restrict__ query,    // [bs, 1, ED]
    const float* __restrict__ ln_g, const float* __restrict__ ln_b,
    const float* __restrict__ ws,       // [bs, 192]
    const int* __restrict__ Hp, const int* __restrict__ Wp,
    float* __restrict__ out,            // [bs, nq, ED]
    int nq, int bs)
{
    const int blk = blockIdx.x;
    const int b = blk % bs;                    // XCD swizzle
    const int qgroup = blk / bs;               // 4 queries per block
    const int t = threadIdx.x;

    __shared__ float s_off[128];
    __shared__ float s_aw[64];
    __shared__ float s_ref[8];                 // 4 queries x (x,y)
    __shared__ __align__(16) float s_c[4 * 64 * 8];  // [q][p][h] x {i00..i11,w00..w11}

    if (t < 128)      s_off[t] = ws[b * 192 + t];
    else if (t < 192) s_aw[t - 128] = ws[b * 192 + t];
    else if (t < 200) {
        const int i = t - 192;                 // i = qL*2 + j
        s_ref[i] = ref2d[(b * nq + qgroup * 4 + (i >> 1)) * 2 + (i & 1)];
    }
    const int H = Hp[0];
    const int W = Wp[0];
    __syncthreads();

    // ---- Phase 1: coordinates/weights, one (qL, h, p) per thread ----
    {
        const int qL = t >> 6;
        const int hp = t & 63;                 // h*8 + p
        const int p  = hp & 7;
        const int h  = hp >> 3;

        const float x = s_ref[qL * 2 + 0] * (float)W - 0.5f + s_off[hp * 2 + 0];
        const float y = s_ref[qL * 2 + 1] * (float)H - 0.5f + s_off[hp * 2 + 1];
        const float aw = s_aw[hp];

        const float xf = floorf(x);
        const float yf = floorf(y);
        const int ix = (int)xf;
        const int iy = (int)yf;
        const float wx = x - xf;
        const float wy = y - yf;

        const bool vx0 = (ix >= 0) && (ix < W);
        const bool vx1 = (ix + 1 >= 0) && (ix + 1 < W);
        const bool vy0 = (iy >= 0) && (iy < H);
        const bool vy1 = (iy + 1 >= 0) && (iy + 1 < H);
        const int cx0 = min(max(ix, 0), W - 1);
        const int cx1 = min(max(ix + 1, 0), W - 1);
        const int cy0 = min(max(iy, 0), H - 1);
        const int cy1 = min(max(iy + 1, 0), H - 1);

        const int r0 = cy0 * W;
        const int r1 = cy1 * W;
        int4 idx;
        idx.x = r0 + cx0;
        idx.y = r0 + cx1;
        idx.z = r1 + cx0;
        idx.w = r1 + cx1;

        const float awx = aw * wx, awix = aw - awx;     // aw*(1-wx)
        float4 wt;
        wt.x = (vx0 && vy0) ? awix * (1.0f - wy) : 0.0f;
        wt.y = (vx1 && vy0) ? awx  * (1.0f - wy) : 0.0f;
        wt.z = (vx0 && vy1) ? awix * wy          : 0.0f;
        wt.w = (vx1 && vy1) ? awx  * wy          : 0.0f;

        const int e = ((qL * 8 + p) * 8 + h) * 8;       // [q][p][h], 8 dwords
        *(int4*)  (&s_c[e])     = idx;
        *(float4*)(&s_c[e + 4]) = wt;
    }
    __syncthreads();

    // ---- Phase 2: gather. lane = t&63 within wave qL; h = lane>>3, c4 = lane&7 ----
    const int qL   = t >> 6;
    const int lane = t & 63;
    const int h    = lane >> 3;
    const int c4   = lane & 7;
    const int q    = qgroup * 4 + qL;

    const float* fb = feat + (size_t)b * nq * ED + h * DHEAD + c4 * 4;

    float ax = 0.f, ay = 0.f, az = 0.f, aww = 0.f;
    #pragma unroll
    for (int p = 0; p < NPTS; ++p) {
        const int e = ((qL * 8 + p) * 8 + h) * 8;
        const int4   idx = *(const int4*)  (&s_c[e]);
        const float4 wt  = *(const float4*)(&s_c[e + 4]);

        const float4 v0 = *(const float4*)(fb + (size_t)idx.x * ED);
        const float4 v1 = *(const float4*)(fb + (size_t)idx.y * ED);
        const float4 v2 = *(const float4*)(fb + (size_t)idx.z * ED);
        const float4 v3 = *(const float4*)(fb + (size_t)idx.w * ED);

        ax = fmaf(wt.x, v0.x, ax); ay = fmaf(wt.x, v0.y, ay);
        az = fmaf(wt.x, v0.z, az); aww = fmaf(wt.x, v0.w, aww);
        ax = fmaf(wt.y, v1.x, ax); ay = fmaf(wt.y, v1.y, ay);
        az = fmaf(wt.y, v1.z, az); aww = fmaf(wt.y, v1.w, aww);
        ax = fmaf(wt.z, v2.x, ax); ay = fmaf(wt.z, v2.y, ay);
        az = fmaf(wt.z, v2.z, az); aww = fmaf(wt.z, v2.w, aww);
        ax = fmaf(wt.w, v3.x, ax); ay = fmaf(wt.w, v3.y, ay);
        az = fmaf(wt.w, v3.z, az); aww = fmaf(wt.w, v3.w, aww);
    }

    // ---- Phase 3: residual + wave-local LayerNorm (channels = lane*4 .. +3) ----
    const float4 qv = *(const float4*)(query + b * ED + lane * 4);
    const float r0 = ax + qv.x;
    const float r1 = ay + qv.y;
    const float r2 = az + qv.z;
    const float r3 = aww + qv.w;

    float s  = (r0 + r1) + (r2 + r3);
    float ss = fmaf(r0, r0, fmaf(r1, r1, fmaf(r2, r2, r3 * r3)));
    #pragma unroll
    for (int m = 1; m < 64; m <<= 1) {
        s  += __shfl_xor(s, m, 64);
        ss += __shfl_xor(ss, m, 64);
    }
    const float mean = s * (1.0f / ED);
    const float var  = ss * (1.0f / ED) - mean * mean;
    const float inv  = rsqrtf(var + 1e-5f);

    const float4 g = *(const float4*)(ln_g + lane * 4);
    const float4 be = *(const float4*)(ln_b + lane * 4);
    float4 o;
    o.x = (r0 - mean) * inv * g.x + be.x;
    o.y = (r1 - mean) * inv * g.y + be.y;
    o.z = (r2 - mean) * inv * g.z + be.z;
    o.w = (r3 - mean) * inv * g.w + be.w;
    *(float4*)(out + ((size_t)b * nq + q) * ED + lane * 4) = o;
}

extern "C" void kernel_launch(void* const* d_in, const int* in_sizes, int n_in,
                              void* d_out, int out_size, void* d_ws, size_t ws_size,
                              hipStream_t stream)
{
    const float* query  = (const float*)d_in[0];
    const float* feat   = (const float*)d_in[1];
    const float* ref2d  = (const float*)d_in[2];
    const float* W_off  = (const float*)d_in[3];
    const float* b_off  = (const float*)d_in[4];
    const float* W_attn = (const float*)d_in[5];
    const float* b_attn = (const float*)d_in[6];
    const float* ln_g   = (const float*)d_in[7];
    const float* ln_b   = (const float*)d_in[8];
    const int*   Hp     = (const int*)d_in[9];
    const int*   Wp     = (const int*)d_in[10];
    float* out = (float*)d_out;
    float* ws  = (float*)d_ws;

    const int bs = in_sizes[0] / ED;            // 8
    const int nq = in_sizes[2] / (bs * 2);      // h*w = 4096

    precompute_kernel<<<bs, 256, 0, stream>>>(query, W_off, b_off, W_attn, b_attn, ws);
    deform_attn_kernel<<<bs * nq / 4, 256, 0, stream>>>(feat, ref2d, query, ln_g, ln_b,
                                                        ws, Hp, Wp, out, nq, bs);
}